// Round 1
// baseline (372.193 us; speedup 1.0000x reference)
//
#include <hip/hip_runtime.h>
#include <hip/hip_cooperative_groups.h>

#define N_NODES 50000
#define N_EDGES 400000
#define DIM 128
#define N_SCAN_BLK ((N_NODES + 255) / 256)   // 196
#define BUCKET_BLK ((N_EDGES + 255) / 256)   // 1563
#define FC1_BLK ((N_NODES + 63) / 64)        // 782

typedef unsigned short u16;
typedef unsigned int   u32;
typedef __bf16 v8bf  __attribute__((ext_vector_type(8)));
typedef float  f32x4 __attribute__((ext_vector_type(4)));
typedef u16    u16x8 __attribute__((ext_vector_type(8)));

union BF8 { u16x8 u; v8bf b; };

__device__ __forceinline__ float bf2f(u16 u) {
    union { u32 i; float f; } v; v.i = ((u32)u) << 16; return v.f;
}
__device__ __forceinline__ u16 f2bf(float f) {
    union { float f; u32 i; } v; v.f = f; u32 u = v.i;
    return (u16)((u + 0x7FFFu + ((u >> 16) & 1u)) >> 16);  // RNE
}

// ===========================================================================
// Cooperative mega-kernel: the whole pipeline in ONE dispatch.
//   P0 zero counts/gcursor + cast W1/W2 -> sync
//   P1 histogram of dst                  -> sync
//   P2 ticket scan (per-256 tile local scan + atomic base ticket;
//      aggregate later uses end = row_ptr[n] + counts[n], so bases need
//      not be globally monotone -> no two-level scan, one fewer sync)
//                                        -> sync
//   P3 bucket scatter, then fc1 MFMA tiles (overlap naturally per block)
//                                        -> sync
//   P4 aggregate 64 nodes into LDS (bf16) fused with fc2 MFMA from LDS
//      (z never touches global memory)
// ===========================================================================
__global__ __launch_bounds__(256, 3) void mega_kernel(
    const float* __restrict__ x,
    const int* __restrict__ esrc, const int* __restrict__ edst,
    const float* __restrict__ W1, const float* __restrict__ b1,
    const float* __restrict__ W2, const float* __restrict__ b2,
    float* __restrict__ out,
    u16* __restrict__ h, u16* __restrict__ Wb1, u16* __restrict__ Wb2,
    int* __restrict__ counts, int* __restrict__ row_ptr,
    int* __restrict__ cursor, int* __restrict__ esorted,
    int* __restrict__ gcursor)
{
    cooperative_groups::grid_group grid = cooperative_groups::this_grid();
    __shared__ __align__(16) char smem[64 * 136 * 2];   // 17408 B, reused per phase
    u16* xs = (u16*)smem;

    const int nb   = (int)gridDim.x;
    const int bid  = (int)blockIdx.x;
    const int t    = (int)threadIdx.x;
    const int gtid = bid * 256 + t;
    const int gsz  = nb * 256;

    // ---------------- P0: zero + weight cast ----------------
    for (int i = gtid; i < N_NODES; i += gsz) counts[i] = 0;
    for (int i = gtid; i < DIM * DIM; i += gsz) {
        Wb1[i] = f2bf(W1[i]);
        Wb2[i] = f2bf(W2[i]);
    }
    if (gtid == 0) *gcursor = 0;
    grid.sync();

    // ---------------- P1: histogram ----------------
    for (int e = gtid; e < N_EDGES; e += gsz) {
        int dst = edst[e];
        int src = esrc[e];
        if ((unsigned)dst < N_NODES && (unsigned)src < N_NODES)
            atomicAdd(&counts[dst], 1);
    }
    grid.sync();

    // ---------------- P2: ticket scan ----------------
    {
        int* tmp   = (int*)smem;        // 256 ints
        int* sbase = tmp + 256;         // 1 int
        for (int sb = bid; sb < N_SCAN_BLK; sb += nb) {
            int i = sb * 256 + t;
            int v = (i < N_NODES) ? counts[i] : 0;
            tmp[t] = v;
            __syncthreads();
#pragma unroll
            for (int ofs = 1; ofs < 256; ofs <<= 1) {
                int add = (t >= ofs) ? tmp[t - ofs] : 0;
                __syncthreads();
                tmp[t] += add;
                __syncthreads();
            }
            int ex = tmp[t] - v;                 // exclusive local prefix
            if (t == 255) *sbase = atomicAdd(gcursor, tmp[255]);
            __syncthreads();
            if (i < N_NODES) {
                int r = *sbase + ex;
                row_ptr[i] = r;
                cursor[i]  = r;
            }
            __syncthreads();
        }
    }
    grid.sync();

    // ---------------- P3: bucket scatter, then fc1 ----------------
    for (int e = gtid; e < N_EDGES; e += gsz) {
        int src = esrc[e], dst = edst[e];
        if ((unsigned)src < N_NODES && (unsigned)dst < N_NODES) {
            int pos = atomicAdd(&cursor[dst], 1);
            esorted[pos] = src;
        }
    }

    {
        const int wave = t >> 6, lane = t & 63, quad = lane >> 4, l15 = lane & 15;
        const int ch = wave >> 1, rh = wave & 1;

        BF8 barr[4][4];
#pragma unroll
        for (int ct = 0; ct < 4; ++ct)
#pragma unroll
            for (int ks = 0; ks < 4; ++ks)
                barr[ct][ks].u = *(const u16x8*)(
                    Wb1 + (size_t)(ch * 64 + ct * 16 + l15) * DIM + ks * 32 + quad * 8);
        float bv[4];
#pragma unroll
        for (int ct = 0; ct < 4; ++ct) bv[ct] = b1[ch * 64 + ct * 16 + l15];

        for (int tile = bid; tile < FC1_BLK; tile += nb) {
            const int row0 = tile * 64;
            {
                int srow = t >> 2, k0 = (t & 3) * 32;
                int grow = row0 + srow; if (grow >= N_NODES) grow = N_NODES - 1;
                const float* xp = x + (size_t)grow * DIM + k0;
#pragma unroll
                for (int j = 0; j < 4; ++j) {
                    float4 f0 = *(const float4*)(xp + j * 8);
                    float4 f1 = *(const float4*)(xp + j * 8 + 4);
                    u16x8 p;
                    p[0] = f2bf(f0.x); p[1] = f2bf(f0.y); p[2] = f2bf(f0.z); p[3] = f2bf(f0.w);
                    p[4] = f2bf(f1.x); p[5] = f2bf(f1.y); p[6] = f2bf(f1.z); p[7] = f2bf(f1.w);
                    *(u16x8*)&xs[srow * 136 + k0 + j * 8] = p;
                }
            }
            f32x4 acc[2][4];
#pragma unroll
            for (int ct = 0; ct < 4; ++ct) {
                acc[0][ct] = (f32x4){bv[ct], bv[ct], bv[ct], bv[ct]};
                acc[1][ct] = (f32x4){bv[ct], bv[ct], bv[ct], bv[ct]};
            }
            __syncthreads();
#pragma unroll
            for (int ks = 0; ks < 4; ++ks) {
                BF8 a0, a1;
                a0.u = *(const u16x8*)&xs[(rh * 32 +  0 + l15) * 136 + ks * 32 + quad * 8];
                a1.u = *(const u16x8*)&xs[(rh * 32 + 16 + l15) * 136 + ks * 32 + quad * 8];
#pragma unroll
                for (int ct = 0; ct < 4; ++ct) {
                    acc[0][ct] = __builtin_amdgcn_mfma_f32_16x16x32_bf16(
                        a0.b, barr[ct][ks].b, acc[0][ct], 0, 0, 0);
                    acc[1][ct] = __builtin_amdgcn_mfma_f32_16x16x32_bf16(
                        a1.b, barr[ct][ks].b, acc[1][ct], 0, 0, 0);
                }
            }
#pragma unroll
            for (int rt = 0; rt < 2; ++rt)
#pragma unroll
                for (int i = 0; i < 4; ++i) {
                    int row = row0 + rh * 32 + rt * 16 + quad * 4 + i;
                    if (row < N_NODES) {
#pragma unroll
                        for (int ct = 0; ct < 4; ++ct) {
                            int col = ch * 64 + ct * 16 + l15;
                            h[(size_t)row * DIM + col] = f2bf(fmaxf(acc[rt][ct][i], 0.f));
                        }
                    }
                }
            __syncthreads();
        }
    }
    grid.sync();

    // ---------------- P4: aggregate (into LDS) + fc2 fused ----------------
    {
        const int wv = t >> 6, ln = t & 63;
        const int quad = ln >> 4, l15 = ln & 15;
        const int ch = wv >> 1, rh = wv & 1;

        BF8 barr[4][4];
#pragma unroll
        for (int ct = 0; ct < 4; ++ct)
#pragma unroll
            for (int ks = 0; ks < 4; ++ks)
                barr[ct][ks].u = *(const u16x8*)(
                    Wb2 + (size_t)(ch * 64 + ct * 16 + l15) * DIM + ks * 32 + quad * 8);
        float bv[4];
#pragma unroll
        for (int ct = 0; ct < 4; ++ct) bv[ct] = b2[ch * 64 + ct * 16 + l15];

        for (int tile = bid; tile < FC1_BLK; tile += nb) {
            const int row0 = tile * 64;

            // --- phase A: aggregate 16 nodes per wave into xs (bf16) ---
            // preload row_ptr/counts for all 16 nodes via lanes 0..15 + shfl
            int nidx = row0 + wv * 16 + (ln & 15);
            int myStart = 0, myDeg = 0;
            if (nidx < N_NODES) { myStart = row_ptr[nidx]; myDeg = counts[nidx]; }

#pragma unroll 1
            for (int j = 0; j < 16; ++j) {
                const int s = wv * 16 + j;
                const int n = row0 + s;
                const int start = __shfl(myStart, j, 64);
                const int deg   = __shfl(myDeg,   j, 64);
                u32 pack = 0;
                if (n < N_NODES) {
                    const int end = start + deg;
                    float a0 = 0.f, a1 = 0.f;
                    int e = start;
                    for (; e + 8 <= end; e += 8) {
                        int s0 = esorted[e + 0], s1 = esorted[e + 1];
                        int s2 = esorted[e + 2], s3 = esorted[e + 3];
                        int s4 = esorted[e + 4], s5 = esorted[e + 5];
                        int s6 = esorted[e + 6], s7 = esorted[e + 7];
                        u32 v0 = *(const u32*)(h + (size_t)s0 * DIM + ln * 2);
                        u32 v1 = *(const u32*)(h + (size_t)s1 * DIM + ln * 2);
                        u32 v2 = *(const u32*)(h + (size_t)s2 * DIM + ln * 2);
                        u32 v3 = *(const u32*)(h + (size_t)s3 * DIM + ln * 2);
                        u32 v4 = *(const u32*)(h + (size_t)s4 * DIM + ln * 2);
                        u32 v5 = *(const u32*)(h + (size_t)s5 * DIM + ln * 2);
                        u32 v6 = *(const u32*)(h + (size_t)s6 * DIM + ln * 2);
                        u32 v7 = *(const u32*)(h + (size_t)s7 * DIM + ln * 2);
                        a0 += bf2f((u16)v0); a1 += bf2f((u16)(v0 >> 16));
                        a0 += bf2f((u16)v1); a1 += bf2f((u16)(v1 >> 16));
                        a0 += bf2f((u16)v2); a1 += bf2f((u16)(v2 >> 16));
                        a0 += bf2f((u16)v3); a1 += bf2f((u16)(v3 >> 16));
                        a0 += bf2f((u16)v4); a1 += bf2f((u16)(v4 >> 16));
                        a0 += bf2f((u16)v5); a1 += bf2f((u16)(v5 >> 16));
                        a0 += bf2f((u16)v6); a1 += bf2f((u16)(v6 >> 16));
                        a0 += bf2f((u16)v7); a1 += bf2f((u16)(v7 >> 16));
                    }
                    for (; e + 4 <= end; e += 4) {
                        int s0 = esorted[e + 0], s1 = esorted[e + 1];
                        int s2 = esorted[e + 2], s3 = esorted[e + 3];
                        u32 v0 = *(const u32*)(h + (size_t)s0 * DIM + ln * 2);
                        u32 v1 = *(const u32*)(h + (size_t)s1 * DIM + ln * 2);
                        u32 v2 = *(const u32*)(h + (size_t)s2 * DIM + ln * 2);
                        u32 v3 = *(const u32*)(h + (size_t)s3 * DIM + ln * 2);
                        a0 += bf2f((u16)v0); a1 += bf2f((u16)(v0 >> 16));
                        a0 += bf2f((u16)v1); a1 += bf2f((u16)(v1 >> 16));
                        a0 += bf2f((u16)v2); a1 += bf2f((u16)(v2 >> 16));
                        a0 += bf2f((u16)v3); a1 += bf2f((u16)(v3 >> 16));
                    }
                    for (; e < end; ++e) {
                        u32 v = *(const u32*)(h + (size_t)esorted[e] * DIM + ln * 2);
                        a0 += bf2f((u16)v); a1 += bf2f((u16)(v >> 16));
                    }
                    u32 r = *(const u32*)(h + (size_t)n * DIM + ln * 2);
                    float inv = (deg > 0) ? 1.f / (float)deg : 1.f;
                    float z0 = a0 * inv + bf2f((u16)r);
                    float z1 = a1 * inv + bf2f((u16)(r >> 16));
                    pack = (u32)f2bf(z0) | ((u32)f2bf(z1) << 16);
                }
                *(u32*)&xs[s * 136 + ln * 2] = pack;
            }
            __syncthreads();

            // --- phase B: fc2 MFMA straight from LDS ---
            f32x4 acc[2][4];
#pragma unroll
            for (int ct = 0; ct < 4; ++ct) {
                acc[0][ct] = (f32x4){bv[ct], bv[ct], bv[ct], bv[ct]};
                acc[1][ct] = (f32x4){bv[ct], bv[ct], bv[ct], bv[ct]};
            }
#pragma unroll
            for (int ks = 0; ks < 4; ++ks) {
                BF8 a0, a1;
                a0.u = *(const u16x8*)&xs[(rh * 32 +  0 + l15) * 136 + ks * 32 + quad * 8];
                a1.u = *(const u16x8*)&xs[(rh * 32 + 16 + l15) * 136 + ks * 32 + quad * 8];
#pragma unroll
                for (int ct = 0; ct < 4; ++ct) {
                    acc[0][ct] = __builtin_amdgcn_mfma_f32_16x16x32_bf16(
                        a0.b, barr[ct][ks].b, acc[0][ct], 0, 0, 0);
                    acc[1][ct] = __builtin_amdgcn_mfma_f32_16x16x32_bf16(
                        a1.b, barr[ct][ks].b, acc[1][ct], 0, 0, 0);
                }
            }
#pragma unroll
            for (int rt = 0; rt < 2; ++rt)
#pragma unroll
                for (int i = 0; i < 4; ++i) {
                    int row = row0 + rh * 32 + rt * 16 + quad * 4 + i;
                    if (row < N_NODES) {
#pragma unroll
                        for (int ct = 0; ct < 4; ++ct) {
                            int col = ch * 64 + ct * 16 + l15;
                            out[(size_t)row * DIM + col] = acc[rt][ct][i];
                        }
                    }
                }
            __syncthreads();
        }
    }
}

// ===========================================================================
// Fallback pipeline (previous best, 177.6 µs) — used only if cooperative
// launch is unavailable.
// ===========================================================================
__global__ __launch_bounds__(256) void count_cast_kernel(
    const int* __restrict__ edst, int* __restrict__ counts,
    const float* __restrict__ W1, const float* __restrict__ W2,
    u16* __restrict__ Wb1, u16* __restrict__ Wb2)
{
    int bid = blockIdx.x;
    if (bid < BUCKET_BLK) {
        int e = bid * 256 + threadIdx.x;
        if (e >= N_EDGES) return;
        int dst = edst[e];
        if ((unsigned)dst >= N_NODES) return;
        atomicAdd(&counts[dst], 1);
    } else {
        int i = (bid - BUCKET_BLK) * 256 + threadIdx.x;
        if (i < DIM * DIM) {
            Wb1[i] = f2bf(W1[i]);
            Wb2[i] = f2bf(W2[i]);
        }
    }
}

__global__ __launch_bounds__(256) void scan_blocks_kernel(
    const int* __restrict__ counts, int* __restrict__ row_ptr,
    int* __restrict__ bsum)
{
    __shared__ int tmp[256];
    const int t = threadIdx.x;
    const int i = blockIdx.x * 256 + t;
    int v = (i < N_NODES) ? counts[i] : 0;
    tmp[t] = v;
    __syncthreads();
#pragma unroll
    for (int ofs = 1; ofs < 256; ofs <<= 1) {
        int add = (t >= ofs) ? tmp[t - ofs] : 0;
        __syncthreads();
        tmp[t] += add;
        __syncthreads();
    }
    if (i < N_NODES) row_ptr[i] = tmp[t] - v;
    if (t == 255) bsum[blockIdx.x] = tmp[255];
}

__global__ __launch_bounds__(256) void scan_fixup2_kernel(
    const int* __restrict__ bsum, int* __restrict__ row_ptr,
    int* __restrict__ cursor)
{
    __shared__ int tmp[256];
    __shared__ int ex[256];
    const int t = threadIdx.x;
    int v = (t < N_SCAN_BLK) ? bsum[t] : 0;
    tmp[t] = v;
    __syncthreads();
#pragma unroll
    for (int ofs = 1; ofs < 256; ofs <<= 1) {
        int add = (t >= ofs) ? tmp[t - ofs] : 0;
        __syncthreads();
        tmp[t] += add;
        __syncthreads();
    }
    ex[t] = tmp[t] - v;
    __syncthreads();

    int boff = ex[blockIdx.x];
    int i = blockIdx.x * 256 + t;
    if (i < N_NODES) {
        int r = row_ptr[i] + boff;
        row_ptr[i] = r;
        cursor[i]  = r;
    }
    if (i == 0) row_ptr[N_NODES] = N_EDGES;
}

__global__ __launch_bounds__(256, 3) void bucket_fc1_kernel(
    const int* __restrict__ esrc, const int* __restrict__ edst,
    int* __restrict__ cursor, int* __restrict__ esorted,
    const float* __restrict__ x, const u16* __restrict__ Wb,
    const float* __restrict__ b, u16* __restrict__ h)
{
    __shared__ u16 xs[64 * 136];
    const int bid = blockIdx.x;

    if (bid < BUCKET_BLK) {
        int e = bid * 256 + threadIdx.x;
        if (e < N_EDGES) {
            int src = esrc[e], dst = edst[e];
            if ((unsigned)src < N_NODES && (unsigned)dst < N_NODES) {
                int pos = atomicAdd(&cursor[dst], 1);
                esorted[pos] = src;
            }
        }
        return;
    }

    const int t = threadIdx.x;
    const int wave = t >> 6, lane = t & 63, quad = lane >> 4, l15 = lane & 15;
    const int ch = wave >> 1, rh = wave & 1;
    const int row0 = (bid - BUCKET_BLK) * 64;

    BF8 barr[4][4];
#pragma unroll
    for (int ct = 0; ct < 4; ++ct)
#pragma unroll
        for (int ks = 0; ks < 4; ++ks)
            barr[ct][ks].u = *(const u16x8*)(
                Wb + (size_t)(ch * 64 + ct * 16 + l15) * DIM + ks * 32 + quad * 8);

    {
        int srow = t >> 2, k0 = (t & 3) * 32;
        int grow = row0 + srow; if (grow >= N_NODES) grow = N_NODES - 1;
        const float* xp = x + (size_t)grow * DIM + k0;
#pragma unroll
        for (int j = 0; j < 4; ++j) {
            float4 f0 = *(const float4*)(xp + j * 8);
            float4 f1 = *(const float4*)(xp + j * 8 + 4);
            u16x8 p;
            p[0] = f2bf(f0.x); p[1] = f2bf(f0.y); p[2] = f2bf(f0.z); p[3] = f2bf(f0.w);
            p[4] = f2bf(f1.x); p[5] = f2bf(f1.y); p[6] = f2bf(f1.z); p[7] = f2bf(f1.w);
            *(u16x8*)&xs[srow * 136 + k0 + j * 8] = p;
        }
    }

    f32x4 acc[2][4];
#pragma unroll
    for (int ct = 0; ct < 4; ++ct) {
        float bv = b[ch * 64 + ct * 16 + l15];
        acc[0][ct] = (f32x4){bv, bv, bv, bv};
        acc[1][ct] = (f32x4){bv, bv, bv, bv};
    }
    __syncthreads();

#pragma unroll
    for (int ks = 0; ks < 4; ++ks) {
        BF8 a0, a1;
        a0.u = *(const u16x8*)&xs[(rh * 32 +  0 + l15) * 136 + ks * 32 + quad * 8];
        a1.u = *(const u16x8*)&xs[(rh * 32 + 16 + l15) * 136 + ks * 32 + quad * 8];
#pragma unroll
        for (int ct = 0; ct < 4; ++ct) {
            acc[0][ct] = __builtin_amdgcn_mfma_f32_16x16x32_bf16(
                a0.b, barr[ct][ks].b, acc[0][ct], 0, 0, 0);
            acc[1][ct] = __builtin_amdgcn_mfma_f32_16x16x32_bf16(
                a1.b, barr[ct][ks].b, acc[1][ct], 0, 0, 0);
        }
    }

#pragma unroll
    for (int rt = 0; rt < 2; ++rt)
#pragma unroll
        for (int i = 0; i < 4; ++i) {
            int row = row0 + rh * 32 + rt * 16 + quad * 4 + i;
            if (row < N_NODES) {
#pragma unroll
                for (int ct = 0; ct < 4; ++ct) {
                    int col = ch * 64 + ct * 16 + l15;
                    h[(size_t)row * DIM + col] = f2bf(fmaxf(acc[rt][ct][i], 0.f));
                }
            }
        }
}

__global__ __launch_bounds__(256) void aggregate_kernel(
    const int* __restrict__ row_ptr, const int* __restrict__ esorted,
    const u16* __restrict__ h, u16* __restrict__ z)
{
    const int wave = threadIdx.x >> 6;
    const int lane = threadIdx.x & 63;
    const int n = blockIdx.x * 4 + wave;
    if (n >= N_NODES) return;

    const int start = row_ptr[n];
    const int end   = row_ptr[n + 1];

    float a0 = 0.f, a1 = 0.f;
    int e = start;
    for (; e + 8 <= end; e += 8) {
        int s0 = esorted[e + 0], s1 = esorted[e + 1];
        int s2 = esorted[e + 2], s3 = esorted[e + 3];
        int s4 = esorted[e + 4], s5 = esorted[e + 5];
        int s6 = esorted[e + 6], s7 = esorted[e + 7];
        u32 v0 = *(const u32*)(h + (size_t)s0 * DIM + lane * 2);
        u32 v1 = *(const u32*)(h + (size_t)s1 * DIM + lane * 2);
        u32 v2 = *(const u32*)(h + (size_t)s2 * DIM + lane * 2);
        u32 v3 = *(const u32*)(h + (size_t)s3 * DIM + lane * 2);
        u32 v4 = *(const u32*)(h + (size_t)s4 * DIM + lane * 2);
        u32 v5 = *(const u32*)(h + (size_t)s5 * DIM + lane * 2);
        u32 v6 = *(const u32*)(h + (size_t)s6 * DIM + lane * 2);
        u32 v7 = *(const u32*)(h + (size_t)s7 * DIM + lane * 2);
        a0 += bf2f((u16)v0); a1 += bf2f((u16)(v0 >> 16));
        a0 += bf2f((u16)v1); a1 += bf2f((u16)(v1 >> 16));
        a0 += bf2f((u16)v2); a1 += bf2f((u16)(v2 >> 16));
        a0 += bf2f((u16)v3); a1 += bf2f((u16)(v3 >> 16));
        a0 += bf2f((u16)v4); a1 += bf2f((u16)(v4 >> 16));
        a0 += bf2f((u16)v5); a1 += bf2f((u16)(v5 >> 16));
        a0 += bf2f((u16)v6); a1 += bf2f((u16)(v6 >> 16));
        a0 += bf2f((u16)v7); a1 += bf2f((u16)(v7 >> 16));
    }
    for (; e + 4 <= end; e += 4) {
        int s0 = esorted[e + 0], s1 = esorted[e + 1];
        int s2 = esorted[e + 2], s3 = esorted[e + 3];
        u32 v0 = *(const u32*)(h + (size_t)s0 * DIM + lane * 2);
        u32 v1 = *(const u32*)(h + (size_t)s1 * DIM + lane * 2);
        u32 v2 = *(const u32*)(h + (size_t)s2 * DIM + lane * 2);
        u32 v3 = *(const u32*)(h + (size_t)s3 * DIM + lane * 2);
        a0 += bf2f((u16)v0); a1 += bf2f((u16)(v0 >> 16));
        a0 += bf2f((u16)v1); a1 += bf2f((u16)(v1 >> 16));
        a0 += bf2f((u16)v2); a1 += bf2f((u16)(v2 >> 16));
        a0 += bf2f((u16)v3); a1 += bf2f((u16)(v3 >> 16));
    }
    for (; e < end; ++e) {
        u32 v = *(const u32*)(h + (size_t)esorted[e] * DIM + lane * 2);
        a0 += bf2f((u16)v); a1 += bf2f((u16)(v >> 16));
    }

    int deg = end - start;
    float inv = (deg > 0) ? 1.f / (float)deg : 1.f;
    u32 r = *(const u32*)(h + (size_t)n * DIM + lane * 2);
    float z0 = a0 * inv + bf2f((u16)r);
    float z1 = a1 * inv + bf2f((u16)(r >> 16));
    u32 p = (u32)f2bf(z0) | ((u32)f2bf(z1) << 16);
    *(u32*)(z + (size_t)n * DIM + lane * 2) = p;
}

__global__ __launch_bounds__(256, 3) void fc2_mfma(
    const u16* __restrict__ z, const u16* __restrict__ Wb,
    const float* __restrict__ b, float* __restrict__ out)
{
    __shared__ u16 xs[64 * 136];
    const int t = threadIdx.x;
    const int wave = t >> 6, lane = t & 63, quad = lane >> 4, l15 = lane & 15;
    const int ch = wave >> 1, rh = wave & 1;
    const int row0 = blockIdx.x * 64;

    BF8 barr[4][4];
#pragma unroll
    for (int ct = 0; ct < 4; ++ct)
#pragma unroll
        for (int ks = 0; ks < 4; ++ks)
            barr[ct][ks].u = *(const u16x8*)(
                Wb + (size_t)(ch * 64 + ct * 16 + l15) * DIM + ks * 32 + quad * 8);

    {
        int srow = t >> 1, k0 = (t & 1) * 64;
        int grow = row0 + srow; if (grow >= N_NODES) grow = N_NODES - 1;
        const u16* zp = z + (size_t)grow * DIM + k0;
#pragma unroll
        for (int j = 0; j < 8; ++j)
            *(u16x8*)&xs[srow * 136 + k0 + j * 8] = *(const u16x8*)(zp + j * 8);
    }

    f32x4 acc[2][4];
#pragma unroll
    for (int ct = 0; ct < 4; ++ct) {
        float bv = b[ch * 64 + ct * 16 + l15];
        acc[0][ct] = (f32x4){bv, bv, bv, bv};
        acc[1][ct] = (f32x4){bv, bv, bv, bv};
    }
    __syncthreads();

#pragma unroll
    for (int ks = 0; ks < 4; ++ks) {
        BF8 a0, a1;
        a0.u = *(const u16x8*)&xs[(rh * 32 +  0 + l15) * 136 + ks * 32 + quad * 8];
        a1.u = *(const u16x8*)&xs[(rh * 32 + 16 + l15) * 136 + ks * 32 + quad * 8];
#pragma unroll
        for (int ct = 0; ct < 4; ++ct) {
            acc[0][ct] = __builtin_amdgcn_mfma_f32_16x16x32_bf16(
                a0.b, barr[ct][ks].b, acc[0][ct], 0, 0, 0);
            acc[1][ct] = __builtin_amdgcn_mfma_f32_16x16x32_bf16(
                a1.b, barr[ct][ks].b, acc[1][ct], 0, 0, 0);
        }
    }

#pragma unroll
    for (int rt = 0; rt < 2; ++rt)
#pragma unroll
        for (int i = 0; i < 4; ++i) {
            int row = row0 + rh * 32 + rt * 16 + quad * 4 + i;
            if (row < N_NODES) {
#pragma unroll
                for (int ct = 0; ct < 4; ++ct) {
                    int col = ch * 64 + ct * 16 + l15;
                    out[(size_t)row * DIM + col] = acc[rt][ct][i];
                }
            }
        }
}

extern "C" void kernel_launch(void* const* d_in, const int* in_sizes, int n_in,
                              void* d_out, int out_size, void* d_ws, size_t ws_size,
                              hipStream_t stream)
{
    const float* x  = (const float*)d_in[0];
    const int*   ei = (const int*)d_in[1];   // [2][E] int32
    const float* W1 = (const float*)d_in[2];
    const float* b1 = (const float*)d_in[3];
    const float* W2 = (const float*)d_in[4];
    const float* b2 = (const float*)d_in[5];
    float* out = (float*)d_out;

    const int* esrc = ei;
    const int* edst = ei + N_EDGES;

    char* ws = (char*)d_ws;
    size_t off = 0;
    u16* h        = (u16*)(ws + off); off += (size_t)N_NODES * DIM * 2;   // 12.8 MB
    u16* z        = (u16*)(ws + off); off += (size_t)N_NODES * DIM * 2;   // 12.8 MB
    u16* Wb1      = (u16*)(ws + off); off += (size_t)DIM * DIM * 2;       // 32 KB
    u16* Wb2      = (u16*)(ws + off); off += (size_t)DIM * DIM * 2;       // 32 KB
    int* counts   = (int*)(ws + off); off += (size_t)N_NODES * 4;
    int* row_ptr  = (int*)(ws + off); off += (size_t)(N_NODES + 1) * 4;
    int* cursor   = (int*)(ws + off); off += (size_t)N_NODES * 4;
    int* esorted  = (int*)(ws + off); off += (size_t)N_EDGES * 4;
    int* bsum     = (int*)(ws + off); off += (size_t)N_SCAN_BLK * 4;
    int* gcursor  = (int*)(ws + off); off += 4;

    // ---- preferred path: single cooperative mega-kernel ----
    static int coop_grid = -1;
    if (coop_grid < 0) {
        int nbpc = 0;
        if (hipOccupancyMaxActiveBlocksPerMultiprocessor(&nbpc, mega_kernel, 256, 0)
                != hipSuccess)
            nbpc = 0;
        if (nbpc > 0) {
            long g = (long)nbpc * 256;       // 256 CUs on MI355X
            if (g > FC1_BLK) g = FC1_BLK;    // no more blocks than output tiles
            coop_grid = (int)g;
        } else {
            coop_grid = 0;
        }
    }
    if (coop_grid > 0) {
        void* args[] = { (void*)&x, (void*)&esrc, (void*)&edst,
                         (void*)&W1, (void*)&b1, (void*)&W2, (void*)&b2,
                         (void*)&out, (void*)&h, (void*)&Wb1, (void*)&Wb2,
                         (void*)&counts, (void*)&row_ptr, (void*)&cursor,
                         (void*)&esorted, (void*)&gcursor };
        if (hipLaunchCooperativeKernel(mega_kernel, dim3(coop_grid), dim3(256),
                                       args, 0, stream) == hipSuccess)
            return;
        coop_grid = 0;   // don't retry on later captures
    }

    // ---- fallback: previous 6-kernel pipeline ----
    hipMemsetAsync(counts, 0, (size_t)N_NODES * 4, stream);
    count_cast_kernel<<<BUCKET_BLK + 64, 256, 0, stream>>>(
        edst, counts, W1, W2, Wb1, Wb2);
    scan_blocks_kernel<<<N_SCAN_BLK, 256, 0, stream>>>(counts, row_ptr, bsum);
    scan_fixup2_kernel<<<N_SCAN_BLK, 256, 0, stream>>>(bsum, row_ptr, cursor);
    bucket_fc1_kernel<<<BUCKET_BLK + FC1_BLK, 256, 0, stream>>>(
        esrc, edst, cursor, esorted, x, Wb1, b1, h);
    aggregate_kernel<<<(N_NODES + 3) / 4, 256, 0, stream>>>(
        row_ptr, esorted, h, z);
    fc2_mfma<<<(N_NODES + 63) / 64, 256, 0, stream>>>(z, Wb2, b2, out);
}

// Round 2
// 179.253 us; speedup vs baseline: 2.0764x; 2.0764x over previous
//
#include <hip/hip_runtime.h>

#define N_NODES 50000
#define N_EDGES 400000
#define DIM 128
#define BUCKET_BLK ((N_EDGES + 255) / 256)   // 1563
#define FC1_BLK ((N_NODES + 63) / 64)        // 782

typedef unsigned short u16;
typedef unsigned int   u32;
typedef __bf16 v8bf  __attribute__((ext_vector_type(8)));
typedef float  f32x4 __attribute__((ext_vector_type(4)));
typedef u16    u16x8 __attribute__((ext_vector_type(8)));

union BF8 { u16x8 u; v8bf b; };

__device__ __forceinline__ float bf2f(u16 u) {
    union { u32 i; float f; } v; v.i = ((u32)u) << 16; return v.f;
}
__device__ __forceinline__ u16 f2bf(float f) {
    union { float f; u32 i; } v; v.f = f; u32 u = v.i;
    return (u16)((u + 0x7FFFu + ((u >> 16) & 1u)) >> 16);  // RNE
}

// ---------------------------------------------------------------------------
// build + fc1 fused:
//   blocks [0, BUCKET_BLK): per-dst linked-list build (single pass, replaces
//     count+scan+scan+bucket):  old = atomicExch(head[dst], e); pair[e]={old,src}
//   blocks [BUCKET_BLK, +FC1_BLK): fc1 MFMA tile, W1 cast fp32->bf16 in-regs.
// build is latency/atomic-bound, fc1 is MFMA-bound -> co-scheduling overlaps.
// ---------------------------------------------------------------------------
__global__ __launch_bounds__(256, 3) void build_fc1_kernel(
    const int* __restrict__ esrc, const int* __restrict__ edst,
    int* __restrict__ head, int2* __restrict__ pairbuf,
    const float* __restrict__ x, const float* __restrict__ W1,
    const float* __restrict__ b1, u16* __restrict__ h)
{
    __shared__ u16 xs[64 * 136];
    const int bid = blockIdx.x;

    if (bid < BUCKET_BLK) {
        int e = bid * 256 + threadIdx.x;
        if (e < N_EDGES) {
            int src = esrc[e], dst = edst[e];
            if ((unsigned)src < N_NODES && (unsigned)dst < N_NODES) {
                int old = atomicExch(&head[dst], e);
                pairbuf[e] = make_int2(old, src);
            }
        }
        return;
    }

    // ---- fc1 tile ----
    const int t = threadIdx.x;
    const int wave = t >> 6, lane = t & 63, quad = lane >> 4, l15 = lane & 15;
    const int ch = wave >> 1, rh = wave & 1;
    const int row0 = (bid - BUCKET_BLK) * 64;

    // W1 fragments: load fp32 straight from L2, cast to bf16 in registers.
    BF8 barr[4][4];
#pragma unroll
    for (int ct = 0; ct < 4; ++ct)
#pragma unroll
        for (int ks = 0; ks < 4; ++ks) {
            const float* wp = W1 + (size_t)(ch * 64 + ct * 16 + l15) * DIM
                                 + ks * 32 + quad * 8;
            float4 f0 = *(const float4*)wp;
            float4 f1 = *(const float4*)(wp + 4);
            u16x8 p;
            p[0] = f2bf(f0.x); p[1] = f2bf(f0.y); p[2] = f2bf(f0.z); p[3] = f2bf(f0.w);
            p[4] = f2bf(f1.x); p[5] = f2bf(f1.y); p[6] = f2bf(f1.z); p[7] = f2bf(f1.w);
            barr[ct][ks].u = p;
        }

    {
        int srow = t >> 2, k0 = (t & 3) * 32;
        int grow = row0 + srow; if (grow >= N_NODES) grow = N_NODES - 1;
        const float* xp = x + (size_t)grow * DIM + k0;
#pragma unroll
        for (int j = 0; j < 4; ++j) {
            float4 f0 = *(const float4*)(xp + j * 8);
            float4 f1 = *(const float4*)(xp + j * 8 + 4);
            u16x8 p;
            p[0] = f2bf(f0.x); p[1] = f2bf(f0.y); p[2] = f2bf(f0.z); p[3] = f2bf(f0.w);
            p[4] = f2bf(f1.x); p[5] = f2bf(f1.y); p[6] = f2bf(f1.z); p[7] = f2bf(f1.w);
            *(u16x8*)&xs[srow * 136 + k0 + j * 8] = p;
        }
    }

    f32x4 acc[2][4];
#pragma unroll
    for (int ct = 0; ct < 4; ++ct) {
        float bv = b1[ch * 64 + ct * 16 + l15];
        acc[0][ct] = (f32x4){bv, bv, bv, bv};
        acc[1][ct] = (f32x4){bv, bv, bv, bv};
    }
    __syncthreads();

#pragma unroll
    for (int ks = 0; ks < 4; ++ks) {
        BF8 a0, a1;
        a0.u = *(const u16x8*)&xs[(rh * 32 +  0 + l15) * 136 + ks * 32 + quad * 8];
        a1.u = *(const u16x8*)&xs[(rh * 32 + 16 + l15) * 136 + ks * 32 + quad * 8];
#pragma unroll
        for (int ct = 0; ct < 4; ++ct) {
            acc[0][ct] = __builtin_amdgcn_mfma_f32_16x16x32_bf16(
                a0.b, barr[ct][ks].b, acc[0][ct], 0, 0, 0);
            acc[1][ct] = __builtin_amdgcn_mfma_f32_16x16x32_bf16(
                a1.b, barr[ct][ks].b, acc[1][ct], 0, 0, 0);
        }
    }

#pragma unroll
    for (int rt = 0; rt < 2; ++rt)
#pragma unroll
        for (int i = 0; i < 4; ++i) {
            int row = row0 + rh * 32 + rt * 16 + quad * 4 + i;
            if (row < N_NODES) {
#pragma unroll
                for (int ct = 0; ct < 4; ++ct) {
                    int col = ch * 64 + ct * 16 + l15;
                    h[(size_t)row * DIM + col] = f2bf(fmaxf(acc[rt][ct][i], 0.f));
                }
            }
        }
}

// ---------------------------------------------------------------------------
// aggregate via linked-list chase: one wave per node, lane owns 2 dims.
// Per step: one broadcast 8B pair load; the 256B row gather is issued off it
// and the NEXT pair load is software-pipelined ahead of the accumulate.
// z[n] = mean(h[src]) + h[n]   (fp32 accumulate, bf16 store)
// ---------------------------------------------------------------------------
__global__ __launch_bounds__(256) void aggregate_kernel(
    const int* __restrict__ head, const int2* __restrict__ pairbuf,
    const u16* __restrict__ h, u16* __restrict__ z)
{
    const int wave = threadIdx.x >> 6;
    const int lane = threadIdx.x & 63;
    const int n = blockIdx.x * 4 + wave;
    if (n >= N_NODES) return;

    float a0 = 0.f, a1 = 0.f;
    int deg = 0;
    int e = head[n];
    if (e >= 0) {
        int2 p = pairbuf[e];
        while (true) {
            const int en  = p.x;
            const int src = p.y;
            // issue row gather for current edge
            u32 v = *(const u32*)(h + (size_t)src * DIM + lane * 2);
            // prefetch next pair before consuming v
            int2 pn;
            const bool more = (en >= 0);
            if (more) pn = pairbuf[en];
            a0 += bf2f((u16)v); a1 += bf2f((u16)(v >> 16));
            ++deg;
            if (!more) break;
            p = pn;
        }
    }

    float inv = (deg > 0) ? 1.f / (float)deg : 1.f;
    u32 r = *(const u32*)(h + (size_t)n * DIM + lane * 2);
    float z0 = a0 * inv + bf2f((u16)r);
    float z1 = a1 * inv + bf2f((u16)(r >> 16));
    u32 pck = (u32)f2bf(z0) | ((u32)f2bf(z1) << 16);
    *(u32*)(z + (size_t)n * DIM + lane * 2) = pck;
}

// ---------------------------------------------------------------------------
// fc2: out = z @ W2^T + b2 (z bf16, W2 cast fp32->bf16 in-regs, out fp32)
// ---------------------------------------------------------------------------
__global__ __launch_bounds__(256, 3) void fc2_mfma(
    const u16* __restrict__ z, const float* __restrict__ W2,
    const float* __restrict__ b2, float* __restrict__ out)
{
    __shared__ u16 xs[64 * 136];
    const int t = threadIdx.x;
    const int wave = t >> 6, lane = t & 63, quad = lane >> 4, l15 = lane & 15;
    const int ch = wave >> 1, rh = wave & 1;
    const int row0 = blockIdx.x * 64;

    BF8 barr[4][4];
#pragma unroll
    for (int ct = 0; ct < 4; ++ct)
#pragma unroll
        for (int ks = 0; ks < 4; ++ks) {
            const float* wp = W2 + (size_t)(ch * 64 + ct * 16 + l15) * DIM
                                 + ks * 32 + quad * 8;
            float4 f0 = *(const float4*)wp;
            float4 f1 = *(const float4*)(wp + 4);
            u16x8 p;
            p[0] = f2bf(f0.x); p[1] = f2bf(f0.y); p[2] = f2bf(f0.z); p[3] = f2bf(f0.w);
            p[4] = f2bf(f1.x); p[5] = f2bf(f1.y); p[6] = f2bf(f1.z); p[7] = f2bf(f1.w);
            barr[ct][ks].u = p;
        }

    {
        int srow = t >> 1, k0 = (t & 1) * 64;
        int grow = row0 + srow; if (grow >= N_NODES) grow = N_NODES - 1;
        const u16* zp = z + (size_t)grow * DIM + k0;
#pragma unroll
        for (int j = 0; j < 8; ++j)
            *(u16x8*)&xs[srow * 136 + k0 + j * 8] = *(const u16x8*)(zp + j * 8);
    }

    f32x4 acc[2][4];
#pragma unroll
    for (int ct = 0; ct < 4; ++ct) {
        float bv = b2[ch * 64 + ct * 16 + l15];
        acc[0][ct] = (f32x4){bv, bv, bv, bv};
        acc[1][ct] = (f32x4){bv, bv, bv, bv};
    }
    __syncthreads();

#pragma unroll
    for (int ks = 0; ks < 4; ++ks) {
        BF8 a0, a1;
        a0.u = *(const u16x8*)&xs[(rh * 32 +  0 + l15) * 136 + ks * 32 + quad * 8];
        a1.u = *(const u16x8*)&xs[(rh * 32 + 16 + l15) * 136 + ks * 32 + quad * 8];
#pragma unroll
        for (int ct = 0; ct < 4; ++ct) {
            acc[0][ct] = __builtin_amdgcn_mfma_f32_16x16x32_bf16(
                a0.b, barr[ct][ks].b, acc[0][ct], 0, 0, 0);
            acc[1][ct] = __builtin_amdgcn_mfma_f32_16x16x32_bf16(
                a1.b, barr[ct][ks].b, acc[1][ct], 0, 0, 0);
        }
    }

#pragma unroll
    for (int rt = 0; rt < 2; ++rt)
#pragma unroll
        for (int i = 0; i < 4; ++i) {
            int row = row0 + rh * 32 + rt * 16 + quad * 4 + i;
            if (row < N_NODES) {
#pragma unroll
                for (int ct = 0; ct < 4; ++ct) {
                    int col = ch * 64 + ct * 16 + l15;
                    out[(size_t)row * DIM + col] = acc[rt][ct][i];
                }
            }
        }
}

extern "C" void kernel_launch(void* const* d_in, const int* in_sizes, int n_in,
                              void* d_out, int out_size, void* d_ws, size_t ws_size,
                              hipStream_t stream)
{
    const float* x  = (const float*)d_in[0];
    const int*   ei = (const int*)d_in[1];   // [2][E] int32
    const float* W1 = (const float*)d_in[2];
    const float* b1 = (const float*)d_in[3];
    const float* W2 = (const float*)d_in[4];
    const float* b2 = (const float*)d_in[5];
    float* out = (float*)d_out;

    const int* esrc = ei;
    const int* edst = ei + N_EDGES;

    char* ws = (char*)d_ws;
    size_t off = 0;
    u16*  h       = (u16*)(ws + off);  off += (size_t)N_NODES * DIM * 2;   // 12.8 MB
    u16*  z       = (u16*)(ws + off);  off += (size_t)N_NODES * DIM * 2;   // 12.8 MB
    int*  head    = (int*)(ws + off);  off += (size_t)N_NODES * 4;         // 200 KB
    int2* pairbuf = (int2*)(ws + off); off += (size_t)N_EDGES * 8;         // 3.2 MB

    // head = -1 everywhere (0xFF byte pattern)
    hipMemsetAsync(head, 0xFF, (size_t)N_NODES * 4, stream);

    build_fc1_kernel<<<BUCKET_BLK + FC1_BLK, 256, 0, stream>>>(
        esrc, edst, head, pairbuf, x, W1, b1, h);
    aggregate_kernel<<<(N_NODES + 3) / 4, 256, 0, stream>>>(
        head, pairbuf, h, z);
    fc2_mfma<<<(N_NODES + 63) / 64, 256, 0, stream>>>(z, W2, b2, out);
}